// Round 6
// baseline (106.661 us; speedup 1.0000x reference)
//
#include <hip/hip_runtime.h>
#include <math.h>

// Morphological dilation, k=4x4, TF SAME padding (pad top/left=1, bottom/right=2).
// x: (8, 512, 512, 32) fp32 NHWC;  w: (4, 4, 32) fp32;  out: same as x.
// out[b,y,x,c] = max_{i,j} x[b, y+i-1, x+j-1, c] + w[i,j,c]  (OOB -> -inf)
//
// R5 post-mortem: ring cut traffic (FETCH 188 MB) but dur rose — VGPR=32
// showed the compiler kept only one row's px live (MLP=4 loads), and 2048
// blocks = exactly 1 residency round (edge-block tail stretched the chip).
// R6: batch 4 rows of loads (16 loads back-to-back, ~50 VGPR) + CHUNK=64
// (4096 blocks, 2x oversubscription). Ring halo stays 67/64 = 1.047x.

constexpr int H = 512;
constexpr int W = 512;
constexpr int C = 32;
constexpr int CHUNK = 64;   // y rows per thread

template<bool XEDGE>
__device__ __forceinline__ void load_row(const float* __restrict__ xb,
                                         const int yy, const int xp,
                                         float px[4]) {
    const float NI = -INFINITY;
    const bool yok = ((unsigned)yy < (unsigned)H);     // uniform
    const int  yc  = min(max(yy, 0), H - 1);
    const float* rowp = xb + (size_t)yc * (W * C);
#pragma unroll
    for (int j = 0; j < 4; ++j) {
        int xx = xp + j - 1;
        bool ok = yok;
        if (XEDGE) {
            ok = ok & ((unsigned)xx < (unsigned)W);
            xx = min(max(xx, 0), W - 1);
        }
        float v = rowp[(size_t)xx * C];
        px[j] = ok ? v : NI;
    }
}

// Phase P = yy & 3. Slot map (compile-time):
//   out yy+1 -> slot (P+1)&3 (i=0); out yy -> P (i=1);
//   out yy-1 -> (P+3)&3 (i=2);      out yy-2 -> (P+2)&3 (i=3, completed).
template<int P, bool STORE>
__device__ __forceinline__ void accum(float* __restrict__ ob,
                                      const float wv[16], float acc[4],
                                      const float px[4], const int yy) {
    constexpr int S0 = P;
    constexpr int S1 = (P + 1) & 3;
    constexpr int S2 = (P + 2) & 3;
    constexpr int S3 = (P + 3) & 3;

    acc[S1] = fmaxf(acc[S1], fmaxf(fmaxf(px[0] + wv[ 0], px[1] + wv[ 1]),
                                   fmaxf(px[2] + wv[ 2], px[3] + wv[ 3])));
    acc[S0] = fmaxf(acc[S0], fmaxf(fmaxf(px[0] + wv[ 4], px[1] + wv[ 5]),
                                   fmaxf(px[2] + wv[ 6], px[3] + wv[ 7])));
    acc[S3] = fmaxf(acc[S3], fmaxf(fmaxf(px[0] + wv[ 8], px[1] + wv[ 9]),
                                   fmaxf(px[2] + wv[10], px[3] + wv[11])));
    acc[S2] = fmaxf(acc[S2], fmaxf(fmaxf(px[0] + wv[12], px[1] + wv[13]),
                                   fmaxf(px[2] + wv[14], px[3] + wv[15])));

    if (STORE)
        __builtin_nontemporal_store(acc[S2], ob + (size_t)(yy - 2) * (W * C));
    acc[S2] = -INFINITY;   // slot reused for output row yy+2
}

template<bool XEDGE>
__device__ __forceinline__ void chunk_body(const float* __restrict__ xb,
                                           float* __restrict__ ob,
                                           const float wv[16], float acc[4],
                                           const int y0, const int xp) {
    // prologue: rows y0-1, y0, y0+1 — accumulate + reset retired slot, no store
    {
        float p0[4], p1[4], p2[4];
        load_row<XEDGE>(xb, y0 - 1, xp, p0);
        load_row<XEDGE>(xb, y0,     xp, p1);
        load_row<XEDGE>(xb, y0 + 1, xp, p2);
        accum<3, false>(ob, wv, acc, p0, y0 - 1);
        accum<0, false>(ob, wv, acc, p1, y0);
        accum<1, false>(ob, wv, acc, p2, y0 + 1);
    }
    // steady: rows y0+2 .. y0+CHUNK+1 store outputs y0 .. y0+CHUNK-1.
    // 16 loads issued back-to-back (no consumer in between) -> deep MLP.
    for (int s = 0; s < CHUNK; s += 4) {
        const int yy = y0 + 2 + s;
        float p0[4], p1[4], p2[4], p3[4];
        load_row<XEDGE>(xb, yy,     xp, p0);
        load_row<XEDGE>(xb, yy + 1, xp, p1);
        load_row<XEDGE>(xb, yy + 2, xp, p2);
        load_row<XEDGE>(xb, yy + 3, xp, p3);
        accum<2, true>(ob, wv, acc, p0, yy);
        accum<3, true>(ob, wv, acc, p1, yy + 1);
        accum<0, true>(ob, wv, acc, p2, yy + 2);
        accum<1, true>(ob, wv, acc, p3, yy + 3);
    }
}

__global__ __launch_bounds__(256)
void dil2d_kernel(const float* __restrict__ xin,
                  const float* __restrict__ wt,
                  float* __restrict__ out) {
    // thread -> (channel, x): lanes walk c then x -> 256 B contiguous per wave load
    const int c  = threadIdx.x & (C - 1);        // 0..31
    const int xl = threadIdx.x >> 5;             // 0..7
    const int xp = blockIdx.x * 8 + xl;          // 0..511
    const int y0 = blockIdx.y * CHUNK;           // chunk start row (mult of 4)
    const int b  = blockIdx.z;

    // 4x4 weight taps for our channel in registers (16 VGPRs)
    float wv[16];
#pragma unroll
    for (int k = 0; k < 16; ++k)
        wv[k] = wt[k * C + c];

    float acc[4] = { -INFINITY, -INFINITY, -INFINITY, -INFINITY };

    const float* xb = xin + (size_t)b * H * W * C + c;
    float* ob = out + ((size_t)b * H * W + xp) * C + c;

    const bool xedge = (blockIdx.x == 0) || (blockIdx.x == gridDim.x - 1);
    if (xedge) chunk_body<true >(xb, ob, wv, acc, y0, xp);
    else       chunk_body<false>(xb, ob, wv, acc, y0, xp);
}

extern "C" void kernel_launch(void* const* d_in, const int* in_sizes, int n_in,
                              void* d_out, int out_size, void* d_ws, size_t ws_size,
                              hipStream_t stream) {
    const float* x = (const float*)d_in[0];
    const float* w = (const float*)d_in[1];
    float* o = (float*)d_out;

    dim3 block(256);
    dim3 grid(W / 8,        // 64: x tiles (8 x-positions per block)
              H / CHUNK,    // 8:  y chunks
              8);           // batch
    dil2d_kernel<<<grid, block, 0, stream>>>(x, w, o);
}

// Round 7
// 101.467 us; speedup vs baseline: 1.0512x; 1.0512x over previous
//
#include <hip/hip_runtime.h>
#include <math.h>

// Morphological dilation, k=4x4, TF SAME padding (pad top/left=1, bottom/right=2).
// x: (8, 512, 512, 32) fp32 NHWC;  w: (4, 4, 32) fp32;  out: same as x.
// out[b,y,x,c] = max_{i,j} x[b, y+i-1, x+j-1, c] + w[i,j,c]  (OOB -> -inf)
//
// Structure lesson (R4 vs R5/R6): the fully-unrolled strip body sustains
// 6.0 TB/s effective; runtime-loop ring structures drop to 4.3 TB/s because
// the compiler sinks loads to uses (VGPR=32 both times) and loses MLP.
// R7: strip with T=32 (halo 35/32 = 1.094x, vs 1.19x at T=16). No
// __launch_bounds__: let the allocator take the 96-VGPR tier rather than
// spill (R2 lesson: don't fight the allocator; give it room).

constexpr int H = 512;
constexpr int W = 512;
constexpr int C = 32;
constexpr int T = 32;  // output rows per thread (y-strip)

template<bool EDGE>
__device__ __forceinline__ void dil_body(const float* __restrict__ xb,
                                         const float wv[16],
                                         float acc[T],
                                         const int y0, const int xp) {
    const float NI = -INFINITY;
#pragma unroll
    for (int r = 0; r < T + 3; ++r) {
        int yy = y0 - 1 + r;
        bool yok = true;
        if (EDGE) {
            yok = ((unsigned)yy < (unsigned)H);
            yy = min(max(yy, 0), H - 1);          // safe clamped address
        }
        const float* rowp = xb + (size_t)yy * (W * C);

        float px[4];
#pragma unroll
        for (int j = 0; j < 4; ++j) {
            int xx = xp + j - 1;
            if (EDGE) {
                bool ok = yok & ((unsigned)xx < (unsigned)W);
                xx = min(max(xx, 0), W - 1);
                float v = rowp[(size_t)xx * C];
                px[j] = ok ? v : NI;
            } else {
                px[j] = rowp[(size_t)xx * C];
            }
        }

#pragma unroll
        for (int i = 0; i < 4; ++i) {
            const int t = r - i;            // unroll-constant: static acc index
            if (t < 0 || t >= T) continue;  // folded at compile time
            float v = fmaxf(fmaxf(px[0] + wv[i * 4 + 0], px[1] + wv[i * 4 + 1]),
                            fmaxf(px[2] + wv[i * 4 + 2], px[3] + wv[i * 4 + 3]));
            acc[t] = fmaxf(acc[t], v);
        }
    }
}

__global__ void dil2d_kernel(const float* __restrict__ xin,
                             const float* __restrict__ wt,
                             float* __restrict__ out) {
    // thread -> (channel, x): lanes walk c then x -> 256 B contiguous per wave load
    const int c  = threadIdx.x & (C - 1);        // 0..31
    const int xl = threadIdx.x >> 5;             // 0..7
    const int xp = blockIdx.x * 8 + xl;          // 0..511
    const int y0 = blockIdx.y * T;               // strip start row
    const int b  = blockIdx.z;

    // hoist the 4x4 weight taps for our channel into registers (16 VGPRs)
    float wv[16];
#pragma unroll
    for (int k = 0; k < 16; ++k)
        wv[k] = wt[k * C + c];

    float acc[T];
#pragma unroll
    for (int t = 0; t < T; ++t) acc[t] = -INFINITY;

    const float* xb = xin + (size_t)b * H * W * C + c;

    // wave-uniform edge classification: interior blocks take the
    // zero-bounds-logic straight-line path.
    const bool yedge = (blockIdx.y == 0) || (blockIdx.y == gridDim.y - 1);
    const bool xedge = (blockIdx.x == 0) || (blockIdx.x == gridDim.x - 1);

    if (yedge | xedge) dil_body<true >(xb, wv, acc, y0, xp);
    else               dil_body<false>(xb, wv, acc, y0, xp);

    float* ob = out + (((size_t)b * H + y0) * W + xp) * C + c;
#pragma unroll
    for (int t = 0; t < T; ++t)
        __builtin_nontemporal_store(acc[t], ob + (size_t)t * W * C);
}

extern "C" void kernel_launch(void* const* d_in, const int* in_sizes, int n_in,
                              void* d_out, int out_size, void* d_ws, size_t ws_size,
                              hipStream_t stream) {
    const float* x = (const float*)d_in[0];
    const float* w = (const float*)d_in[1];
    float* o = (float*)d_out;

    dim3 block(256);
    dim3 grid(W / 8,    // 64: x tiles (8 x-positions per block)
              H / T,    // 16: y strips
              8);       // batch
    dil2d_kernel<<<grid, block, 0, stream>>>(x, w, o);
}